// Round 1
// 508.991 us; speedup vs baseline: 6.2491x; 6.2491x over previous
//
#include <hip/hip_runtime.h>

// ADI diffusion: 2048 images of 128x128 fp32, 10 steps of (x half, y full,
// x half) tridiagonal solves. Factorizations are batch-independent ->
// precomputed per substep into g_FG by factor_kernel. Main kernel keeps the
// whole image in LDS (fp32, padded stride 132) and each line in REGISTERS
// during a solve.
//
// R1 change vs previous session best (3180 us): the per-thread line buffer
// r[128] was generating ~9.4 GB of scratch writes per dispatch (WRITE_SIZE
// 9.37e6 KB vs 1.4e5 KB ideal) -> the float4 address-punning on &r[4q] and
// lambda-by-reference captures defeated SROA and the array lived in local
// memory. Rewritten: sessions are __forceinline__ functions, r[128] scoped
// per-session, vector accesses only on LDS pointers (element-wise unpack),
// REPS is a template parameter. r must end up in VGPRs/AGPRs.

#define EPSF 1e-6f
#define STR 132   // 128 + 4 pad: x-sweeps b128 conflict-free, y-sweeps b32 2-way (free)

__device__ float g_FG[30 * 256];   // per substep: F[128] then G[128]

// One block per substep s (0..29). coeff = smooth3(clip(base+lin*t+quad*t^2, EPS))*dt,
// then Thomas factorization: F_i = 1/dn_i, G_i = coeff_i/dn_i (cs_i = -G_i).
__global__ void factor_kernel(const float* __restrict__ abx,
                              const float* __restrict__ atx,
                              const float* __restrict__ aqx,
                              const float* __restrict__ bby,
                              const float* __restrict__ bty,
                              const float* __restrict__ bqy) {
  const int s = blockIdx.x;        // 0..29
  const int i = threadIdx.x;       // 0..127
  const int step = s / 3, phase = s - 3 * step;
  const float t  = 0.005f * (float)(2 * step + phase);
  const float dt = (phase == 1) ? 0.01f : 0.005f;
  const float* vb = (phase == 1) ? bby : abx;
  const float* vl = (phase == 1) ? bty : atx;
  const float* vq = (phase == 1) ? bqy : aqx;

  __shared__ float vv[128];
  __shared__ float cf[128];

  float v = vb[i] + vl[i] * t + vq[i] * t * t;
  v = fmaxf(v, EPSF);
  vv[i] = v;
  __syncthreads();
  float lft = vv[(i == 0)   ? 0   : (i - 1)];
  float rgt = vv[(i == 127) ? 127 : (i + 1)];
  cf[i] = (lft + v + rgt) * (1.0f / 3.0f) * dt;
  __syncthreads();

  if (i == 0) {
    float* Fo = g_FG + s * 256;
    float* Go = Fo + 128;
    float c0 = cf[0];
    float denom = 1.0f + c0 + EPSF;   // b[0] = 1 + coeff[0], + EPS
    float f = 1.0f / denom;
    float g = c0 * f;
    Fo[0] = f; Go[0] = g;
    float cs = -g;                    // cs_0 = c0/denom0
    for (int k = 1; k < 128; k++) {
      float ck = cf[k];
      float b  = (k == 127) ? (1.0f + ck) : (1.0f + 2.0f * ck);
      float dn = b + ck * cs + EPSF;  // b - a*cs + EPS, a = -coeff
      float fk = 1.0f / dn;
      float gk = ck * fk;
      Fo[k] = fk; Go[k] = gk;
      cs = -gk;
    }
  }
}

// Thomas substitution on a line held in registers.
// fwd: ds_i = d_i*F_i + G_i*ds_{i-1};  bwd: x_i = ds_i + G_i*x_{i+1}
__device__ __forceinline__ void solve_line(float (&r)[128],
                                           const float* __restrict__ Fs,
                                           const float* __restrict__ Gs) {
  r[0] *= Fs[0];
  #pragma unroll
  for (int i = 1; i < 128; i++) r[i] = fmaf(Gs[i], r[i - 1], r[i] * Fs[i]);
  #pragma unroll
  for (int i = 126; i >= 0; i--) r[i] = fmaf(Gs[i], r[i + 1], r[i]);
}

// x-direction: thread tid owns row tid. REPS=2 merges the (same-matrix)
// end-of-step / start-of-next-step half solves into one register session.
// NOTE: vector loads only address LDS; r is written element-wise so the
// alloca never has its address taken (SROA-safe).
template <int REPS>
__device__ __forceinline__ void x_session(float* __restrict__ sm, int tid,
                                          const float* __restrict__ FG) {
  float r[128];
  #pragma unroll
  for (int q = 0; q < 32; q++) {
    float4 t = *(const float4*)&sm[tid * STR + 4 * q];
    r[4 * q + 0] = t.x; r[4 * q + 1] = t.y;
    r[4 * q + 2] = t.z; r[4 * q + 3] = t.w;
  }
  #pragma unroll
  for (int rep = 0; rep < REPS; rep++) solve_line(r, FG, FG + 128);
  #pragma unroll
  for (int q = 0; q < 32; q++) {
    float4 t;
    t.x = r[4 * q + 0]; t.y = r[4 * q + 1];
    t.z = r[4 * q + 2]; t.w = r[4 * q + 3];
    *(float4*)&sm[tid * STR + 4 * q] = t;
  }
}

// y-direction: thread tid owns column tid (b32 LDS, 2-way = free).
__device__ __forceinline__ void y_session(float* __restrict__ sm, int tid,
                                          const float* __restrict__ FG) {
  float r[128];
  #pragma unroll
  for (int h = 0; h < 128; h++) r[h] = sm[h * STR + tid];
  solve_line(r, FG, FG + 128);
  #pragma unroll
  for (int h = 0; h < 128; h++) sm[h * STR + tid] = r[h];
}

__global__ __launch_bounds__(128, 1) void diffusion_kernel(
    const float* __restrict__ uin,
    float* __restrict__ uout) {
  extern __shared__ float sm[];   // 128 * 132 floats = 66 KiB
  const int tid = threadIdx.x;
  const long long ibase = (long long)blockIdx.x << 14;   // 16384 elems per image

  // ---- load image into LDS (float4, coalesced 16B/lane) ----
  #pragma unroll
  for (int k = 0; k < 16384; k += 512) {
    int idx = k + tid * 4;
    int h = idx >> 7, w = idx & 127;
    *(float4*)&sm[h * STR + w] = *(const float4*)(uin + ibase + idx);
  }
  __syncthreads();

  // substep sequence: x(s=0); per step k: y(s=3k+1); x(s=3k+2) merged with
  // s=3k+3 (identical t -> identical factors), last one single.
  x_session<1>(sm, tid, g_FG);
  __syncthreads();
  #pragma unroll 1
  for (int k = 0; k < 10; k++) {
    y_session(sm, tid, g_FG + (3 * k + 1) * 256);
    __syncthreads();
    if (k < 9) x_session<2>(sm, tid, g_FG + (3 * k + 2) * 256);
    else       x_session<1>(sm, tid, g_FG + (3 * k + 2) * 256);
    __syncthreads();
  }

  // ---- store (float4, coalesced) ----
  #pragma unroll
  for (int k = 0; k < 16384; k += 512) {
    int idx = k + tid * 4;
    int h = idx >> 7, w = idx & 127;
    *(float4*)(uout + ibase + idx) = *(const float4*)&sm[h * STR + w];
  }
}

extern "C" void kernel_launch(void* const* d_in, const int* in_sizes, int n_in,
                              void* d_out, int out_size, void* d_ws, size_t ws_size,
                              hipStream_t stream) {
  const float* u   = (const float*)d_in[0];
  const float* abx = (const float*)d_in[1];
  const float* bby = (const float*)d_in[4];
  const float* atx = (const float*)d_in[5];
  const float* bty = (const float*)d_in[8];
  const float* aqx = (const float*)d_in[9];
  const float* bqy = (const float*)d_in[12];
  float* out = (float*)d_out;

  factor_kernel<<<30, 128, 0, stream>>>(abx, atx, aqx, bby, bty, bqy);
  diffusion_kernel<<<2048, 128, STR * 128 * sizeof(float), stream>>>(u, out);
}